// Round 2
// baseline (574.465 us; speedup 1.0000x reference)
//
#include <hip/hip_runtime.h>

// Problem constants (from reference): L=6, B=32, T=64, K=64, F=80
#define NL 6
#define NB 32
#define NT 64
#define NK 64
#define NF 80
#define BT 2048          // NB*NT
#define NWAVE (NL * BT)  // 12288 (one wave per (l,b,t))
#define NBLK (NWAVE / 4) // 3072 blocks, 4 waves each
#define LAST_BLK_START 2560 // blocks with blockIdx >= 5*512 handle layer 5

// Normalized DS_W for L=6: [0.2,0.2,0.2,0.4,0.4,0.4] / 1.8
#define W_LOW  (0.2f / 1.8f)
#define W_HIGH (0.4f / 1.8f)

// ---------------------------------------------------------------------------
// Kernel A: per-(b,t) validity and 1/max(n_elem,1)
// ---------------------------------------------------------------------------
__global__ __launch_bounds__(256) void prep_kernel(
    const int* __restrict__ tfv,     // (BT, NF) 0/1
    const int* __restrict__ tmask,   // (BT,)    0/1
    float* __restrict__ wvalid,      // (BT,)
    float* __restrict__ winvne) {    // (BT,)
  int bt = blockIdx.x * blockDim.x + threadIdx.x;
  if (bt >= BT) return;
  const int* p = tfv + bt * NF;
  int cnt = 0;
#pragma unroll 8
  for (int f = 0; f < NF; ++f) cnt += (p[f] != 0) ? 1 : 0;
  float valid = (tmask[bt] != 0 && cnt > 0) ? 1.0f : 0.0f;
  wvalid[bt] = valid;
  winvne[bt] = 1.0f / fmaxf(2.0f * (float)cnt, 1.0f);
}

// ---------------------------------------------------------------------------
// Kernel B: one wave per (l,b,t). Lane k = mode k.
//   - argmin over endpoint distances (butterfly, tie-break lower k)
//   - logsumexp over scores, ce = logz - score[best_k]
//   - smooth-L1 over best trajectory (lanes cooperate over F)
// Per-block partial (4 waves, all same layer) written to part[blockIdx].
// ---------------------------------------------------------------------------
__global__ __launch_bounds__(256) void main_kernel(
    const float* __restrict__ trajs,   // (L,B,T,K,F,2)
    const float* __restrict__ scores,  // (L,B,T,K)
    const float* __restrict__ tf,      // (B,T,F,2)
    const int* __restrict__ tfv,       // (B,T,F)
    const float* __restrict__ wvalid,  // (BT,)
    const float* __restrict__ winvne,  // (BT,)
    float* __restrict__ part) {        // (NBLK,)
  __shared__ float warr[4];
  const int wid = threadIdx.x >> 6;
  const int lane = threadIdx.x & 63;
  const int wglb = blockIdx.x * 4 + wid;   // == lbt index (l*BT + bt)
  const int l = wglb >> 11;                // / 2048
  const int bt = wglb & (BT - 1);

  // ground-truth endpoint (broadcast across wave, L2-resident)
  const float2 ge = *reinterpret_cast<const float2*>(tf + (bt * NF + (NF - 1)) * 2);

  // my mode's endpoint: trajs[lbt, k=lane, f=NF-1, :]
  const int base = wglb * (NK * NF * 2);   // wglb*10240, max ~1.26e8 < 2^31
  const float2 pe = *reinterpret_cast<const float2*>(
      trajs + base + lane * (NF * 2) + (NF - 1) * 2);
  float dx = pe.x - ge.x, dy = pe.y - ge.y;
  float d2 = dx * dx + dy * dy;
  int bk = lane;

  float s = scores[wglb * NK + lane];

  // wave argmin (first-min semantics via lower-k tie-break)
#pragma unroll
  for (int off = 32; off > 0; off >>= 1) {
    float od = __shfl_xor(d2, off);
    int ok = __shfl_xor(bk, off);
    if (od < d2 || (od == d2 && ok < bk)) { d2 = od; bk = ok; }
  }

  // logsumexp over scores
  float m = s;
#pragma unroll
  for (int off = 32; off > 0; off >>= 1) m = fmaxf(m, __shfl_xor(m, off));
  float se = expf(s - m);
#pragma unroll
  for (int off = 32; off > 0; off >>= 1) se += __shfl_xor(se, off);
  float ce = m + logf(se) - __shfl(s, bk);

  // smooth-L1 over best trajectory; lanes cover f = lane, lane+64
  const float* btra = trajs + base + bk * (NF * 2);
  float rsum = 0.0f;
#pragma unroll
  for (int f = lane; f < NF; f += 64) {
    float2 p = *reinterpret_cast<const float2*>(btra + f * 2);
    float2 g = *reinterpret_cast<const float2*>(tf + (bt * NF + f) * 2);
    if (tfv[bt * NF + f] != 0) {
      float ax = fabsf(p.x - g.x);
      rsum += (ax < 1.0f) ? 0.5f * ax * ax : ax - 0.5f;
      float ay = fabsf(p.y - g.y);
      rsum += (ay < 1.0f) ? 0.5f * ay * ay : ay - 0.5f;
    }
  }
#pragma unroll
  for (int off = 32; off > 0; off >>= 1) rsum += __shfl_xor(rsum, off);
  float reg = rsum * winvne[bt];

  if (lane == 0) {
    float wl = (l < 3) ? W_LOW : W_HIGH;
    warr[wid] = wl * wvalid[bt] * (ce + reg);
  }
  __syncthreads();
  if (threadIdx.x == 0)
    part[blockIdx.x] = warr[0] + warr[1] + warr[2] + warr[3];
}

// ---------------------------------------------------------------------------
// Kernel C: reduce partials; last layer (blocks >= 2560) divided by n_valid
// ---------------------------------------------------------------------------
__global__ __launch_bounds__(256) void final_kernel(
    const float* __restrict__ part,    // (NBLK,)
    const float* __restrict__ wvalid,  // (BT,)
    float* __restrict__ out) {
  __shared__ float sA[4], sB[4], sN[4];
  int tid = threadIdx.x;
  float a = 0.0f, bl = 0.0f, nv = 0.0f;
  for (int i = tid; i < NBLK; i += 256) {
    float v = part[i];
    if (i < LAST_BLK_START) a += v; else bl += v;
  }
  for (int i = tid; i < BT; i += 256) nv += wvalid[i];
#pragma unroll
  for (int off = 32; off > 0; off >>= 1) {
    a += __shfl_xor(a, off);
    bl += __shfl_xor(bl, off);
    nv += __shfl_xor(nv, off);
  }
  int wid = tid >> 6, lane = tid & 63;
  if (lane == 0) { sA[wid] = a; sB[wid] = bl; sN[wid] = nv; }
  __syncthreads();
  if (tid == 0) {
    float A = sA[0] + sA[1] + sA[2] + sA[3];
    float Bv = sB[0] + sB[1] + sB[2] + sB[3];
    float N = sN[0] + sN[1] + sN[2] + sN[3];
    out[0] = A + Bv / fmaxf(N, 1.0f);
  }
}

// ---------------------------------------------------------------------------
extern "C" void kernel_launch(void* const* d_in, const int* in_sizes, int n_in,
                              void* d_out, int out_size, void* d_ws, size_t ws_size,
                              hipStream_t stream) {
  const float* trajs  = (const float*)d_in[0];  // (L,B,T,K,F,2) f32
  const float* scores = (const float*)d_in[1];  // (L,B,T,K)     f32
  const float* tf     = (const float*)d_in[2];  // (B,T,F,2)     f32
  const int*   tfv    = (const int*)d_in[3];    // (B,T,F)       bool->int
  const int*   tmask  = (const int*)d_in[4];    // (B,T)         bool->int

  float* ws     = (float*)d_ws;
  float* part   = ws;              // NBLK floats
  float* wvalid = ws + NBLK;       // BT floats
  float* winvne = ws + NBLK + BT;  // BT floats

  float* out = (float*)d_out;

  prep_kernel<<<(BT + 255) / 256, 256, 0, stream>>>(tfv, tmask, wvalid, winvne);
  main_kernel<<<NBLK, 256, 0, stream>>>(trajs, scores, tf, tfv, wvalid, winvne, part);
  final_kernel<<<1, 256, 0, stream>>>(part, wvalid, out);
}

// Round 3
// 569.800 us; speedup vs baseline: 1.0082x; 1.0082x over previous
//
#include <hip/hip_runtime.h>

// Problem constants (from reference): L=6, B=32, T=64, K=64, F=80
#define NL 6
#define NB 32
#define NT 64
#define NK 64
#define NF 80
#define BT 2048          // NB*NT
#define NWAVE (NL * BT)  // 12288 (one wave per (l,b,t))
#define NBLK (NWAVE / 4) // 3072 blocks, 4 waves each
#define LAST_BLK_START 2560 // blocks with blockIdx >= 5*512 handle layer 5

// Normalized DS_W for L=6: [0.2,0.2,0.2,0.4,0.4,0.4] / 1.8
#define W_LOW  (0.2f / 1.8f)
#define W_HIGH (0.4f / 1.8f)

// ---------------------------------------------------------------------------
// Kernel M: one wave per (l,b,t). Lane k = mode k.  Fuses the old prep:
// valid/n_elem are recomputed in-wave from tfv/tmask (L2-resident).
//   - all bk-independent loads issued FIRST (hide endpoint-gather latency)
//   - single merged butterfly: argmin(dist), max(score), sum(valid_cnt)
//   - best-traj gather issued before the logsumexp-sum butterfly
// Layer-0 waves also write wvalid[bt] for the final n_valid reduction.
// ---------------------------------------------------------------------------
__global__ __launch_bounds__(256) void main_kernel(
    const float* __restrict__ trajs,   // (L,B,T,K,F,2)
    const float* __restrict__ scores,  // (L,B,T,K)
    const float* __restrict__ tf,      // (B,T,F,2)
    const int* __restrict__ tfv,       // (B,T,F)
    const int* __restrict__ tmask,     // (B,T)
    float* __restrict__ wvalid,        // (BT,)
    float* __restrict__ part) {        // (NBLK,)
  __shared__ float warr[4];
  const int wid = threadIdx.x >> 6;
  const int lane = threadIdx.x & 63;
  const int wglb = blockIdx.x * 4 + wid;   // == l*BT + bt
  const int l = wglb >> 11;
  const int bt = wglb & (BT - 1);

  // ---- issue every bk-independent load up front ----
  const int base = wglb * (NK * NF * 2);   // max ~1.26e8 < 2^31
  const float2 pe = *reinterpret_cast<const float2*>(
      trajs + base + lane * (NF * 2) + (NF - 1) * 2);       // HBM gather
  const float2 ge = *reinterpret_cast<const float2*>(tf + (bt * NF + (NF - 1)) * 2);
  const float s = scores[wglb * NK + lane];
  const int t0 = tfv[bt * NF + lane];
  const int t1 = (lane < NF - 64) ? tfv[bt * NF + 64 + lane] : 0;
  const float2 g0 = *reinterpret_cast<const float2*>(tf + (bt * NF + lane) * 2);
  float2 g1 = {0.0f, 0.0f};
  if (lane < NF - 64)
    g1 = *reinterpret_cast<const float2*>(tf + (bt * NF + 64 + lane) * 2);
  const int tm = tmask[bt];

  // ---- merged butterfly: argmin(d2, lower-k tie-break) / max(s) / sum(cnt)
  float dx = pe.x - ge.x, dy = pe.y - ge.y;
  float d2 = dx * dx + dy * dy;
  int bk = lane;
  float m = s;
  float c = (float)((t0 != 0) + (t1 != 0));
#pragma unroll
  for (int off = 32; off > 0; off >>= 1) {
    float od = __shfl_xor(d2, off);
    int ok = __shfl_xor(bk, off);
    if (od < d2 || (od == d2 && ok < bk)) { d2 = od; bk = ok; }
    m = fmaxf(m, __shfl_xor(m, off));
    c += __shfl_xor(c, off);
  }

  // ---- issue best-trajectory gather now, overlap with logsumexp-sum ----
  const float* btra = trajs + base + bk * (NF * 2);
  const float2 p0 = *reinterpret_cast<const float2*>(btra + lane * 2);
  float2 p1 = {0.0f, 0.0f};
  if (lane < NF - 64)
    p1 = *reinterpret_cast<const float2*>(btra + (64 + lane) * 2);

  float se = expf(s - m);
#pragma unroll
  for (int off = 32; off > 0; off >>= 1) se += __shfl_xor(se, off);

  // ---- smooth-L1 on the gathered best trajectory ----
  float rsum = 0.0f;
  if (t0 != 0) {
    float ax = fabsf(p0.x - g0.x);
    rsum += (ax < 1.0f) ? 0.5f * ax * ax : ax - 0.5f;
    float ay = fabsf(p0.y - g0.y);
    rsum += (ay < 1.0f) ? 0.5f * ay * ay : ay - 0.5f;
  }
  if (t1 != 0) {
    float ax = fabsf(p1.x - g1.x);
    rsum += (ax < 1.0f) ? 0.5f * ax * ax : ax - 0.5f;
    float ay = fabsf(p1.y - g1.y);
    rsum += (ay < 1.0f) ? 0.5f * ay * ay : ay - 0.5f;
  }
#pragma unroll
  for (int off = 32; off > 0; off >>= 1) rsum += __shfl_xor(rsum, off);

  const float valid = (tm != 0 && c > 0.0f) ? 1.0f : 0.0f;
  const float invne = 1.0f / fmaxf(2.0f * c, 1.0f);
  const float ce = m + logf(se) - __shfl(s, bk);

  if (lane == 0) {
    if (wglb < BT) wvalid[bt] = valid;  // layer-0 waves cover each bt once
    const float wl = (l < 3) ? W_LOW : W_HIGH;
    warr[wid] = wl * valid * (ce + rsum * invne);
  }
  __syncthreads();
  if (threadIdx.x == 0)
    part[blockIdx.x] = warr[0] + warr[1] + warr[2] + warr[3];
}

// ---------------------------------------------------------------------------
// Kernel F: reduce partials; last layer (blocks >= 2560) divided by n_valid
// ---------------------------------------------------------------------------
__global__ __launch_bounds__(256) void final_kernel(
    const float* __restrict__ part,    // (NBLK,)
    const float* __restrict__ wvalid,  // (BT,)
    float* __restrict__ out) {
  __shared__ float sA[4], sB[4], sN[4];
  int tid = threadIdx.x;
  float a = 0.0f, bl = 0.0f, nv = 0.0f;
  for (int i = tid; i < NBLK; i += 256) {
    float v = part[i];
    if (i < LAST_BLK_START) a += v; else bl += v;
  }
  for (int i = tid; i < BT; i += 256) nv += wvalid[i];
#pragma unroll
  for (int off = 32; off > 0; off >>= 1) {
    a += __shfl_xor(a, off);
    bl += __shfl_xor(bl, off);
    nv += __shfl_xor(nv, off);
  }
  int wid = tid >> 6, lane = tid & 63;
  if (lane == 0) { sA[wid] = a; sB[wid] = bl; sN[wid] = nv; }
  __syncthreads();
  if (tid == 0) {
    float A = sA[0] + sA[1] + sA[2] + sA[3];
    float Bv = sB[0] + sB[1] + sB[2] + sB[3];
    float N = sN[0] + sN[1] + sN[2] + sN[3];
    out[0] = A + Bv / fmaxf(N, 1.0f);
  }
}

// ---------------------------------------------------------------------------
extern "C" void kernel_launch(void* const* d_in, const int* in_sizes, int n_in,
                              void* d_out, int out_size, void* d_ws, size_t ws_size,
                              hipStream_t stream) {
  const float* trajs  = (const float*)d_in[0];  // (L,B,T,K,F,2) f32
  const float* scores = (const float*)d_in[1];  // (L,B,T,K)     f32
  const float* tf     = (const float*)d_in[2];  // (B,T,F,2)     f32
  const int*   tfv    = (const int*)d_in[3];    // (B,T,F)       bool->int
  const int*   tmask  = (const int*)d_in[4];    // (B,T)         bool->int

  float* ws     = (float*)d_ws;
  float* part   = ws;              // NBLK floats
  float* wvalid = ws + NBLK;       // BT floats

  float* out = (float*)d_out;

  main_kernel<<<NBLK, 256, 0, stream>>>(trajs, scores, tf, tfv, tmask, wvalid, part);
  final_kernel<<<1, 256, 0, stream>>>(part, wvalid, out);
}